// Round 6
// baseline (240.843 us; speedup 1.0000x reference)
//
#include <hip/hip_runtime.h>
#include <math.h>

#define PATCH 96
#define STRIDE 48
#define NH 21
#define NW 21
#define NP (NH * NW)              // 441 patches per (b,c)
#define BATCH 8
#define CHAN 4
#define NBC (BATCH * CHAN)        // 32
#define IMG_H 1056
#define IMG_W 1056
#define ROWF 1056                 // floats per image row
#define NHB 44                    // 24-row half-bands
#define NCHUNK 22                 // 48-col chunks
#define NSTAT 6                   // s1, s2, gxi, gxb, gyi, gyb
#define NPIX 9216.0f
#define NGRAD 9120.0f
#define SLAB (NHB * NCHUNK * NSTAT)   // 5808 floats per bc
#define NR 5                      // LDS row-slot ring depth per wave
#define PF 4                      // prefetch distance (rows ahead)

typedef __attribute__((address_space(3))) unsigned int lds_uint;
typedef __attribute__((address_space(1))) const unsigned int glb_uint;

// async global->LDS, 16B per lane; LDS dest = wave-uniform base + lane*16
__device__ __forceinline__ void stage16(const float* g, float* l) {
  __builtin_amdgcn_global_load_lds((glb_uint*)g, (lds_uint*)l, 16, 0, 0);
}

// ---------------------------------------------------------------------------
// Phase 1: one block per (bc, half-band), 320 threads (264 active own 4 cols).
// History: R0 register loop = latency-bound (~90 us: in-flight depth is
// VGPR-bound). R5 gload_lds + __syncthreads dbuf = WORSE (~100 us): the
// compiler's vmcnt(0) drain at every barrier collapses the pipeline (the §5
// barrier-drain stall). This round: WAVE-PRIVATE counted-vmcnt ring, zero
// barriers in the row loop (T3/T4 "never vmcnt(0) in the main loop"):
//   * each wave stages its own 64x16B row slice into its own 5-slot LDS ring
//   * gx neighbor = per-lane scalar global load (L2 hit), issued PF=4 rows
//     ahead into a register ring (constant indices only -> stays in VGPRs)
//   * per step: ISSUE(r+4) [2 VMEM], s_waitcnt vmcnt(8) [retires pair r,
//     in-order retirement], consume row r from LDS. Epilogue 6/4/2/0.
//   * asm memory clobbers pin each iteration's VMEM between waits -> counts
//     are schedule-robust; no cross-wave data -> no barriers needed.
// In-flight/CU ~ 6 blk x 5 waves x 4 rows x 1KB ~ 120 KB >> 9.2 KB needed.
// Inactive lanes (t>=264) stage clamped duplicates into allocated-but-unread
// LDS (keeps exec!=0 -> uniform VMEM issue count per wave).
// ---------------------------------------------------------------------------
__global__ __launch_bounds__(320) void band_stats_kernel(
    const float* __restrict__ x, float* __restrict__ pfo, int* __restrict__ cnt) {
  __shared__ float L[5 * NR * 256];       // 5 waves x 5 slots x 1024 B = 25.6 KB
  __shared__ float acc[NCHUNK * NSTAT];   // 528 B

  const int t = threadIdx.x;              // 0..319
  const int bc = blockIdx.x / NHB;
  const int hb = blockIdx.x - bc * NHB;
  // zero the phase-2 ticket counter (poisoned workspace)
  if (blockIdx.x == 0 && t == 0) cnt[0] = 0;

  const bool active = t < 264;
  const int tc = active ? t : 263;        // clamp idle lanes to a safe column
  // neighbor offset: +4 except image edge (noff=3 -> d4==0, lands in the
  // never-read gxb of chunk 21)
  const int noff = (tc == 263) ? 3 : 4;
  const int lane = t & 63;
  const int wave = t >> 6;

  const float* base = x + (size_t)bc * (IMG_H * IMG_W);
  const int row0 = hb * 24;
  float* Lw = &L[wave * (NR * 256)];      // wave-uniform slot region

  float s1 = 0.f, s2 = 0.f, gxi = 0.f, gxb = 0.f, gyi = 0.f, gyb = 0.f;
  const bool bnd_is_gxb = ((tc % 12) == 11);   // last quad of its chunk
  float4 prev{0.f, 0.f, 0.f, 0.f};             // r==0 guard ensures unused
  float nxt[NR];                               // neighbor register ring

  // row 24 exists only as the gyb partner; hb==43 clamps it to row 23 (gyb=0)
#define GROWN(r) (((r) == 24 && hb == NHB - 1) ? (row0 + 23) : (row0 + (r)))

#define ISSUE(r)                                                         \
  do {                                                                   \
    const float* g_ = base + (size_t)GROWN(r) * ROWF + 4 * tc;           \
    stage16(g_, Lw + ((r) % NR) * 256);                                  \
    nxt[(r) % NR] = g_[noff];                                            \
  } while (0)

#define SUMS_GX(A, nx)                                                   \
  do {                                                                   \
    s1 += (A).x + (A).y + (A).z + (A).w;                                 \
    s2 += (A).x * (A).x + (A).y * (A).y + (A).z * (A).z + (A).w * (A).w; \
    float d1 = (A).y - (A).x, d2 = (A).z - (A).y, d3 = (A).w - (A).z;    \
    float d4 = (nx) - (A).w;                                             \
    gxi += d1 * d1 + d2 * d2 + d3 * d3;                                  \
    float bd = d4 * d4;                                                  \
    if (bnd_is_gxb) gxb += bd; else gxi += bd;                           \
  } while (0)

#define CONSUME(r)                                                       \
  do {                                                                   \
    const float4 A = *(const float4*)(Lw + ((r) % NR) * 256 + lane * 4); \
    if ((r) < 24) SUMS_GX(A, nxt[(r) % NR]);                             \
    if ((r) > 0) {                                                       \
      const float e0 = A.x - prev.x, e1 = A.y - prev.y,                  \
                  e2 = A.z - prev.z, e3 = A.w - prev.w;                  \
      const float sq = e0 * e0 + e1 * e1 + e2 * e2 + e3 * e3;            \
      if ((r) < 24) gyi += sq; else gyb += sq;                           \
    }                                                                    \
    prev = A;                                                            \
  } while (0)

  // STEP(r, w): issue pair r+PF, wait to <=w outstanding (retires pair r:
  // in-order retirement), consume row r. w literal for the asm immediate.
#define STEP(r, w)                                                       \
  do {                                                                   \
    if ((r) + PF <= 24) ISSUE((r) + PF);                                 \
    asm volatile("s_waitcnt vmcnt(" #w ")" ::: "memory");                \
    CONSUME(r);                                                          \
  } while (0)

  ISSUE(0); ISSUE(1); ISSUE(2); ISSUE(3);          // 8 VMEM outstanding
  STEP(0, 8);  STEP(1, 8);  STEP(2, 8);  STEP(3, 8);  STEP(4, 8);
  STEP(5, 8);  STEP(6, 8);  STEP(7, 8);  STEP(8, 8);  STEP(9, 8);
  STEP(10, 8); STEP(11, 8); STEP(12, 8); STEP(13, 8); STEP(14, 8);
  STEP(15, 8); STEP(16, 8); STEP(17, 8); STEP(18, 8); STEP(19, 8);
  STEP(20, 8);                                      // last issue: pair 24
  STEP(21, 6); STEP(22, 4); STEP(23, 2); STEP(24, 0);
#undef STEP
#undef CONSUME
#undef SUMS_GX
#undef ISSUE
#undef GROWN

  for (int i = t; i < NCHUNK * NSTAT; i += 320) acc[i] = 0.f;
  __syncthreads();
  if (active) {
    const int chunk = tc / 12;
    atomicAdd(&acc[chunk * NSTAT + 0], s1);
    atomicAdd(&acc[chunk * NSTAT + 1], s2);
    atomicAdd(&acc[chunk * NSTAT + 2], gxi);
    atomicAdd(&acc[chunk * NSTAT + 3], gxb);
    atomicAdd(&acc[chunk * NSTAT + 4], gyi);
    atomicAdd(&acc[chunk * NSTAT + 5], gyb);
  }
  __syncthreads();
  float* dst = pfo + (size_t)(bc * NHB + hb) * (NCHUNK * NSTAT);
  for (int i = t; i < NCHUNK * NSTAT; i += 320) dst[i] = acc[i];
}

// ---------------------------------------------------------------------------
// Phase 2+3 merged: one block per bc (32 blocks). Proven in rounds 2-3.
// ---------------------------------------------------------------------------
__global__ __launch_bounds__(512) void patch_finalize_kernel(
    const float* __restrict__ pf, float* __restrict__ featsG,
    int* __restrict__ cnt, const float* __restrict__ mu0_full,
    const float* __restrict__ cov_full, float* __restrict__ out) {
  __shared__ float S[SLAB];                   // 23.2 KB
  __shared__ float wsum[8][3];
  __shared__ double inv_s[12][12];
  __shared__ float fin_s[96 + BATCH];
  __shared__ int ticket_s;

  const int bc = blockIdx.x;
  const int t = threadIdx.x;
  const float* src = pf + (size_t)bc * SLAB;
  for (int i = t; i < SLAB; i += 512) S[i] = src[i];
  __syncthreads();

  float fmu = 0.f, fvar = 0.f, fg = 0.f;
  if (t < NP) {
    const int ph = t / NW, pw = t - ph * NW;
    const int h0 = 2 * ph;
#define AT(h, c, s) S[((h) * NCHUNK + (c)) * NSTAT + (s)]
    float S1 = 0.f, S2 = 0.f, Gx = 0.f, Gy = 0.f;
#pragma unroll
    for (int hh = 0; hh < 4; ++hh) {
      const int h = h0 + hh;
      S1 += AT(h, pw, 0) + AT(h, pw + 1, 0);
      S2 += AT(h, pw, 1) + AT(h, pw + 1, 1);
      Gx += AT(h, pw, 2) + AT(h, pw, 3) + AT(h, pw + 1, 2);
      Gy += AT(h, pw, 4) + AT(h, pw + 1, 4);
    }
#pragma unroll
    for (int hh = 0; hh < 3; ++hh) {
      const int h = h0 + hh;
      Gy += AT(h, pw, 5) + AT(h, pw + 1, 5);
    }
#undef AT
    fmu = S1 / NPIX;
    fvar = (S2 - S1 * S1 / NPIX) / (NPIX - 1.f);
    fg = sqrtf((Gx + Gy) / NGRAD);
  }
#pragma unroll
  for (int off = 32; off > 0; off >>= 1) {
    fmu += __shfl_xor(fmu, off);
    fvar += __shfl_xor(fvar, off);
    fg += __shfl_xor(fg, off);
  }
  const int wave = t >> 6;
  if ((t & 63) == 0) { wsum[wave][0] = fmu; wsum[wave][1] = fvar; wsum[wave][2] = fg; }
  __syncthreads();
  if (t == 0) {
    float m = 0.f, v = 0.f, g = 0.f;
#pragma unroll
    for (int w = 0; w < 8; ++w) { m += wsum[w][0]; v += wsum[w][1]; g += wsum[w][2]; }
    const int b = bc / CHAN, c = bc - b * CHAN;
    featsG[b * 12 + 0 + c] = m / (float)NP;
    featsG[b * 12 + 4 + c] = v / (float)NP;
    featsG[b * 12 + 8 + c] = g / (float)NP;
    __threadfence();                      // release featsG (32 fences: cheap)
    ticket_s = atomicAdd(cnt, 1);         // device-scope ticket
  }
  __syncthreads();
  if (ticket_s != NBC - 1) return;

  // ---- last block: finalize ----
  __threadfence();                        // acquire
  if (t < 96)
    fin_s[t] = __hip_atomic_load(&featsG[t], __ATOMIC_RELAXED,
                                 __HIP_MEMORY_SCOPE_AGENT);
  __syncthreads();

  if (t < 64) {   // wave 0: register-resident Gauss-Jordan, lane c owns col c
    double M[12];
#pragma unroll
    for (int r = 0; r < 12; ++r) {
      double v = 0.0;
      if (t < 12) v = (double)cov_full[r * 36 + t];
      else if (t < 24) v = (t - 12 == r) ? 1.0 : 0.0;
      M[r] = v;
    }
#pragma unroll
    for (int k = 0; k < 12; ++k) {
      const double piv = __shfl(M[k], k);
      const double ip = 1.0 / piv;
      M[k] *= ip;
#pragma unroll
      for (int r = 0; r < 12; ++r) {
        if (r == k) continue;
        const double f = __shfl(M[r], k);   // old M[r][k], read before update
        M[r] -= f * M[k];
      }
    }
    if (t >= 12 && t < 24) {
      const int j = t - 12;
#pragma unroll
      for (int r = 0; r < 12; ++r) inv_s[r][j] = M[r];
    }
  }
  __syncthreads();

  if (t < BATCH) {
    double acc = 0.0;
    double d[12];
#pragma unroll
    for (int i = 0; i < 12; ++i)
      d[i] = (double)fin_s[t * 12 + i] - (double)mu0_full[i];
#pragma unroll
    for (int i = 0; i < 12; ++i) {
      double row = 0.0;
#pragma unroll
      for (int j = 0; j < 12; ++j) row += inv_s[i][j] * d[j];
      acc += d[i] * row;
    }
    fin_s[96 + t] = (float)sqrt(acc);
  }
  __syncthreads();
  if (t == 0) {
    float m = 0.f;
#pragma unroll
    for (int b = 0; b < BATCH; ++b) m += fin_s[96 + b];
    out[0] = m / (float)BATCH;
  }
}

extern "C" void kernel_launch(void* const* d_in, const int* in_sizes, int n_in,
                              void* d_out, int out_size, void* d_ws, size_t ws_size,
                              hipStream_t stream) {
  const float* x   = (const float*)d_in[0];
  const float* mu0 = (const float*)d_in[1];
  const float* cov = (const float*)d_in[2];
  float* out = (float*)d_out;
  float* pf     = (float*)d_ws;                         // 32*5808 floats = 743 KB
  float* featsG = pf + (size_t)NBC * SLAB;              // 96 floats
  int* cnt      = (int*)(featsG + 96);                  // 1 ticket counter

  band_stats_kernel<<<NBC * NHB, 320, 0, stream>>>(x, pf, cnt);
  patch_finalize_kernel<<<NBC, 512, 0, stream>>>(pf, featsG, cnt, mu0, cov, out);
}

// Round 7
// 230.868 us; speedup vs baseline: 1.0432x; 1.0432x over previous
//
#include <hip/hip_runtime.h>
#include <math.h>

#define PATCH 96
#define STRIDE 48
#define NH 21
#define NW 21
#define NP (NH * NW)              // 441 patches per (b,c)
#define BATCH 8
#define CHAN 4
#define NBC (BATCH * CHAN)        // 32
#define IMG_H 1056
#define IMG_W 1056
#define ROWF 1056
#define NHB 44                    // 24-row half-bands
#define NQ 264                    // float4 quad-columns per row
#define NCHUNK 22                 // 48-col chunks (12 qcols)
#define NSTAT 6                   // s1, s2, gxi, gxb, gyi, gyb
#define NPIX 9216.0f
#define NGRAD 9120.0f
#define CSLAB (NHB * NCHUNK * NSTAT)  // 5808 chunk-stats per bc
#define QSLAB (NHB * NSTAT * NQ)      // 69696 qcol-stats per bc
#define NTHREADS (NBC * NHB * NQ)     // 371712 = 1452 * 256

// ---------------------------------------------------------------------------
// Phase 1 "strip" kernel: ONE THREAD per (bc, half-band, qcol). Pure
// streaming: no LDS, no barriers, no atomics, no idle lanes, minimal VGPR.
// Rationale (R0/R5/R6 post-mortems): three different load schedules all
// landed at 88-97 us because achieved occupancy was ~4 waves/CU (13%) — the
// 1408x(5-wave,264/320-active,LDS+barrier) block shape itself limited
// residency. This shape removes every residency limiter: 1452 x 256-thread
// blocks, 22.7 waves/CU potential, each thread 25 float4 + 25 scalar
// independent loads, 6 accumulators, coalesced stores.
// Per-qcol stats (gxb = own d4^2 sum -> no chunk-boundary branch);
// qcol->chunk reduction moved to patch kernel pass 1.
// ---------------------------------------------------------------------------
__global__ __launch_bounds__(256) void strip_stats_kernel(
    const float* __restrict__ x, float* __restrict__ pf, int* __restrict__ cnt) {
  const int g = blockIdx.x * 256 + threadIdx.x;   // 0..371711, no tail
  if (g == 0) cnt[0] = 0;                         // re-arm phase-2 ticket

  const int qcol = g % NQ;
  const int bh = g / NQ;                          // (bc*44 + hb)
  const int hb = bh % NHB;
  // neighbor offset: +4 except image edge (noff=3 -> d4==0; qcol 263's gxb
  // is never read by pass 2: pw max is 20 -> chunks 0..20 only)
  const int noff = (qcol == NQ - 1) ? 3 : 4;

  const float* rowbase = x + (size_t)(bh / NHB) * (IMG_H * IMG_W)
                           + (size_t)(hb * 24) * ROWF + 4 * qcol;

  float s1 = 0.f, s2 = 0.f, gxi = 0.f, gxb = 0.f, gyi = 0.f, gyb = 0.f;

#define SUMS_GX(A, nx)                                                   \
  do {                                                                   \
    s1 += (A).x + (A).y + (A).z + (A).w;                                 \
    s2 += (A).x * (A).x + (A).y * (A).y + (A).z * (A).z + (A).w * (A).w; \
    float d1 = (A).y - (A).x, d2 = (A).z - (A).y, d3 = (A).w - (A).z;    \
    float d4 = (nx) - (A).w;                                             \
    gxi += d1 * d1 + d2 * d2 + d3 * d3;                                  \
    gxb += d4 * d4;                                                      \
  } while (0)

  float4 prev;
  {  // row 0 (no gy)
    const float4 A = *(const float4*)rowbase;
    const float nxt = rowbase[noff];
    SUMS_GX(A, nxt);
    prev = A;
  }
#pragma unroll
  for (int r = 1; r < 24; ++r) {
    const float4 A = *(const float4*)(rowbase + (size_t)r * ROWF);
    const float nxt = rowbase[(size_t)r * ROWF + noff];
    SUMS_GX(A, nxt);
    const float e0 = A.x - prev.x, e1 = A.y - prev.y,
                e2 = A.z - prev.z, e3 = A.w - prev.w;
    gyi += e0 * e0 + e1 * e1 + e2 * e2 + e3 * e3;
    prev = A;
  }
  {  // boundary gy pair: row 23 <-> row 24; hb==43 clamps to row 23 -> 0
    const int r24 = (hb == NHB - 1) ? 23 : 24;
    const float4 A = *(const float4*)(rowbase + (size_t)r24 * ROWF);
    const float e0 = A.x - prev.x, e1 = A.y - prev.y,
                e2 = A.z - prev.z, e3 = A.w - prev.w;
    gyb = e0 * e0 + e1 * e1 + e2 * e2 + e3 * e3;
  }
#undef SUMS_GX

  // coalesced stores: [bc][hb][stat][qcol]
  float* dst = pf + (size_t)bh * (NSTAT * NQ) + qcol;
  dst[0 * NQ] = s1;
  dst[1 * NQ] = s2;
  dst[2 * NQ] = gxi;
  dst[3 * NQ] = gxb;
  dst[4 * NQ] = gyi;
  dst[5 * NQ] = gyb;
}

// ---------------------------------------------------------------------------
// Phase 2+3: one block per bc (32 blocks).
// Pass 1: qcol->chunk reduction (reads the bc's 279 KB slab from L2/L3):
//   chunk gxi = sum(gxi_q, 12) + sum(gxb_q, q=0..10); chunk gxb = gxb_q11;
//   others = plain 12-sums. Builds the same [hb][chunk][stat] slab in LDS.
// Pass 2 + ticket + finalize: proven R3 code verbatim.
// ---------------------------------------------------------------------------
__global__ __launch_bounds__(512) void patch_finalize_kernel(
    const float* __restrict__ pf, float* __restrict__ featsG,
    int* __restrict__ cnt, const float* __restrict__ mu0_full,
    const float* __restrict__ cov_full, float* __restrict__ out) {
  __shared__ float S[CSLAB];                  // 23.2 KB
  __shared__ float wsum[8][3];
  __shared__ double inv_s[12][12];
  __shared__ float fin_s[96 + BATCH];
  __shared__ int ticket_s;

  const int bc = blockIdx.x;
  const int t = threadIdx.x;
  const float* pb = pf + (size_t)bc * QSLAB;

  // ---- pass 1: qcol -> chunk ----
  for (int i = t; i < CSLAB; i += 512) {
    const int hb = i / (NCHUNK * NSTAT);
    const int rem = i - hb * (NCHUNK * NSTAT);
    const int c = rem / NSTAT;
    const int s = rem - c * NSTAT;
    const float* q = pb + (size_t)(hb * NSTAT + s) * NQ + 12 * c;
    float v;
    if (s == 3) {
      v = q[11];                              // chunk gxb = last quad's d4^2
    } else {
      v = 0.f;
#pragma unroll
      for (int k = 0; k < 12; ++k) v += q[k];
      if (s == 2) {                           // gxi absorbs gxb of quads 0..10
        const float* qb = q + NQ;             // stat 3 row
#pragma unroll
        for (int k = 0; k < 11; ++k) v += qb[k];
      }
    }
    S[i] = v;
  }
  __syncthreads();

  // ---- pass 2: per-patch features (proven R3 code) ----
  float fmu = 0.f, fvar = 0.f, fg = 0.f;
  if (t < NP) {
    const int ph = t / NW, pw = t - ph * NW;
    const int h0 = 2 * ph;
#define AT(h, c, s) S[((h) * NCHUNK + (c)) * NSTAT + (s)]
    float S1 = 0.f, S2 = 0.f, Gx = 0.f, Gy = 0.f;
#pragma unroll
    for (int hh = 0; hh < 4; ++hh) {
      const int h = h0 + hh;
      S1 += AT(h, pw, 0) + AT(h, pw + 1, 0);
      S2 += AT(h, pw, 1) + AT(h, pw + 1, 1);
      Gx += AT(h, pw, 2) + AT(h, pw, 3) + AT(h, pw + 1, 2);
      Gy += AT(h, pw, 4) + AT(h, pw + 1, 4);
    }
#pragma unroll
    for (int hh = 0; hh < 3; ++hh) {
      const int h = h0 + hh;
      Gy += AT(h, pw, 5) + AT(h, pw + 1, 5);
    }
#undef AT
    fmu = S1 / NPIX;
    fvar = (S2 - S1 * S1 / NPIX) / (NPIX - 1.f);
    fg = sqrtf((Gx + Gy) / NGRAD);
  }
#pragma unroll
  for (int off = 32; off > 0; off >>= 1) {
    fmu += __shfl_xor(fmu, off);
    fvar += __shfl_xor(fvar, off);
    fg += __shfl_xor(fg, off);
  }
  const int wave = t >> 6;
  if ((t & 63) == 0) { wsum[wave][0] = fmu; wsum[wave][1] = fvar; wsum[wave][2] = fg; }
  __syncthreads();
  if (t == 0) {
    float m = 0.f, v = 0.f, g = 0.f;
#pragma unroll
    for (int w = 0; w < 8; ++w) { m += wsum[w][0]; v += wsum[w][1]; g += wsum[w][2]; }
    const int b = bc / CHAN, c = bc - b * CHAN;
    featsG[b * 12 + 0 + c] = m / (float)NP;
    featsG[b * 12 + 4 + c] = v / (float)NP;
    featsG[b * 12 + 8 + c] = g / (float)NP;
    __threadfence();                      // release featsG (32 fences: cheap)
    ticket_s = atomicAdd(cnt, 1);         // device-scope ticket
  }
  __syncthreads();
  if (ticket_s != NBC - 1) return;

  // ---- last block: finalize ----
  __threadfence();                        // acquire
  if (t < 96)
    fin_s[t] = __hip_atomic_load(&featsG[t], __ATOMIC_RELAXED,
                                 __HIP_MEMORY_SCOPE_AGENT);
  __syncthreads();

  if (t < 64) {   // wave 0: register-resident Gauss-Jordan, lane c owns col c
    double M[12];
#pragma unroll
    for (int r = 0; r < 12; ++r) {
      double v = 0.0;
      if (t < 12) v = (double)cov_full[r * 36 + t];
      else if (t < 24) v = (t - 12 == r) ? 1.0 : 0.0;
      M[r] = v;
    }
#pragma unroll
    for (int k = 0; k < 12; ++k) {
      const double piv = __shfl(M[k], k);
      const double ip = 1.0 / piv;
      M[k] *= ip;
#pragma unroll
      for (int r = 0; r < 12; ++r) {
        if (r == k) continue;
        const double f = __shfl(M[r], k);   // old M[r][k], read before update
        M[r] -= f * M[k];
      }
    }
    if (t >= 12 && t < 24) {
      const int j = t - 12;
#pragma unroll
      for (int r = 0; r < 12; ++r) inv_s[r][j] = M[r];
    }
  }
  __syncthreads();

  if (t < BATCH) {
    double acc = 0.0;
    double d[12];
#pragma unroll
    for (int i = 0; i < 12; ++i)
      d[i] = (double)fin_s[t * 12 + i] - (double)mu0_full[i];
#pragma unroll
    for (int i = 0; i < 12; ++i) {
      double row = 0.0;
#pragma unroll
      for (int j = 0; j < 12; ++j) row += inv_s[i][j] * d[j];
      acc += d[i] * row;
    }
    fin_s[96 + t] = (float)sqrt(acc);
  }
  __syncthreads();
  if (t == 0) {
    float m = 0.f;
#pragma unroll
    for (int b = 0; b < BATCH; ++b) m += fin_s[96 + b];
    out[0] = m / (float)BATCH;
  }
}

extern "C" void kernel_launch(void* const* d_in, const int* in_sizes, int n_in,
                              void* d_out, int out_size, void* d_ws, size_t ws_size,
                              hipStream_t stream) {
  const float* x   = (const float*)d_in[0];
  const float* mu0 = (const float*)d_in[1];
  const float* cov = (const float*)d_in[2];
  float* out = (float*)d_out;
  float* pf     = (float*)d_ws;                         // 32*69696 floats = 8.9 MB
  float* featsG = pf + (size_t)NBC * QSLAB;             // 96 floats
  int* cnt      = (int*)(featsG + 96);                  // 1 ticket counter

  strip_stats_kernel<<<NTHREADS / 256, 256, 0, stream>>>(x, pf, cnt);
  patch_finalize_kernel<<<NBC, 512, 0, stream>>>(pf, featsG, cnt, mu0, cov, out);
}

// Round 11
// 227.120 us; speedup vs baseline: 1.0604x; 1.0165x over previous
//
#include <hip/hip_runtime.h>
#include <math.h>

#define PATCH 96
#define STRIDE 48
#define NH 21
#define NW 21
#define NP (NH * NW)              // 441 patches per (b,c)
#define BATCH 8
#define CHAN 4
#define NBC (BATCH * CHAN)        // 32
#define IMG_H 1056
#define IMG_W 1056
#define NHB 44                    // 24-row half-bands
#define NCHUNK 22                 // 48-col chunks
#define NSTAT 6                   // s1, s2, gxi, gxb, gyi, gyb
#define NPIX 9216.0f
#define NGRAD 9120.0f
#define SLAB (NHB * NCHUNK * NSTAT)   // 5808 floats per bc

// ---------------------------------------------------------------------------
// FINAL (reverted to round-3 best-known-good, measured 228.0 us, passed).
// Session findings baked into comments so future sessions don't re-walk
// falsified paths:
//  * ~167 us/iter is harness poison-fill (2x 84 us @ 85% HBM) — untouchable.
//  * Phase 1 is pinned at ~1.6 TB/s effective across FIVE structures (ILP
//    loop / shfl neighbor / barrier-dbuf gload_lds / counted-vmcnt ring /
//    1-thread-per-strip streaming). Falsified levers: VMEM instruction
//    count, barrier drain, fence cost, block-shape residency.
//  * min-waves launch_bounds forces VGPR=32 -> serialized loads (5% BW).
//  * __threadfence per block scales catastrophically (1408x wbl2 = +75 us);
//    32x is free.
//  * Register-staged deep-load variants (25-row and 13-row batches) hit 3
//    consecutive container failures — never measured; avoid resubmitting.
// ---------------------------------------------------------------------------
__global__ __launch_bounds__(320) void band_stats_kernel(
    const float* __restrict__ x, float* __restrict__ pf, int* __restrict__ cnt) {
  __shared__ float acc[NCHUNK * NSTAT];   // 528 B

  const int t = threadIdx.x;              // 0..319
  const int bc = blockIdx.x / NHB;
  const int hb = blockIdx.x - bc * NHB;
  // zero the phase-2 ticket counter (poisoned workspace); visible to the next
  // kernel via the dispatch boundary
  if (blockIdx.x == 0 && t == 0) cnt[0] = 0;

  const bool active = t < 264;
  const int tc = active ? t : 263;        // clamp idle lanes to a safe column
  // right-neighbor offset: +4 except at image edge (clamped -> d4==0, lands
  // in the never-read gxb of chunk 21)
  const int noff = (tc == 263) ? 3 : 4;

  const float* rowbase = x + (size_t)bc * (IMG_H * IMG_W)
                           + (size_t)(hb * 24) * IMG_W
                           + (size_t)(4 * tc);

  float s1 = 0.f, s2 = 0.f, gxi = 0.f, gxb = 0.f, gyi = 0.f, gyb = 0.f;
  const bool bnd_is_gxb = ((tc % 12) == 11);   // last quad of its chunk

#define SUMS_GX(A, nxt)                                                  \
  do {                                                                   \
    s1 += (A).x + (A).y + (A).z + (A).w;                                 \
    s2 += (A).x * (A).x + (A).y * (A).y + (A).z * (A).z + (A).w * (A).w; \
    float d1 = (A).y - (A).x, d2 = (A).z - (A).y, d3 = (A).w - (A).z;    \
    float d4 = (nxt) - (A).w;                                            \
    gxi += d1 * d1 + d2 * d2 + d3 * d3;                                  \
    float bd = d4 * d4;                                                  \
    if (bnd_is_gxb) gxb += bd; else gxi += bd;                           \
  } while (0)

  float4 prev;
  {  // row 0 (no gy)
    const float4 A = *(const float4*)rowbase;
    const float nxt = rowbase[noff];
    SUMS_GX(A, nxt);
    prev = A;
  }
#pragma unroll 4
  for (int r = 1; r < 24; ++r) {
    const float4 A = *(const float4*)(rowbase + (size_t)r * IMG_W);
    const float nxt = rowbase[(size_t)r * IMG_W + noff];
    SUMS_GX(A, nxt);
    const float e0 = A.x - prev.x, e1 = A.y - prev.y,
                e2 = A.z - prev.z, e3 = A.w - prev.w;
    gyi += e0 * e0 + e1 * e1 + e2 * e2 + e3 * e3;
    prev = A;
  }
  if (hb != NHB - 1) {   // boundary gy pair (row 23 <-> row 24 == next hb's row 0)
    const float4 A = *(const float4*)(rowbase + (size_t)24 * IMG_W);
    const float e0 = A.x - prev.x, e1 = A.y - prev.y,
                e2 = A.z - prev.z, e3 = A.w - prev.w;
    gyb = e0 * e0 + e1 * e1 + e2 * e2 + e3 * e3;
  }
#undef SUMS_GX

  for (int i = t; i < NCHUNK * NSTAT; i += 320) acc[i] = 0.f;
  __syncthreads();
  if (active) {
    const int chunk = tc / 12;
    atomicAdd(&acc[chunk * NSTAT + 0], s1);
    atomicAdd(&acc[chunk * NSTAT + 1], s2);
    atomicAdd(&acc[chunk * NSTAT + 2], gxi);
    atomicAdd(&acc[chunk * NSTAT + 3], gxb);
    atomicAdd(&acc[chunk * NSTAT + 4], gyi);
    atomicAdd(&acc[chunk * NSTAT + 5], gyb);
  }
  __syncthreads();
  float* dst = pf + (size_t)(bc * NHB + hb) * (NCHUNK * NSTAT);
  for (int i = t; i < NCHUNK * NSTAT; i += 320) dst[i] = acc[i];
}

// ---------------------------------------------------------------------------
// Phase 2+3 merged: one block per bc (32 blocks). Stage the bc's 44x22x6 slab
// in LDS; thread p<441 combines its 4 half-bands x 2 chunks into
// (mu, var, gmag); block-reduce to per-bc means -> featsG. The last-arriving
// block (device-scope ticket; only 32 fences, cheap) then runs the
// register-resident Gauss-Jordan + Mahalanobis finalize. Validated rounds 2-3.
// ---------------------------------------------------------------------------
__global__ __launch_bounds__(512) void patch_finalize_kernel(
    const float* __restrict__ pf, float* __restrict__ featsG,
    int* __restrict__ cnt, const float* __restrict__ mu0_full,
    const float* __restrict__ cov_full, float* __restrict__ out) {
  __shared__ float S[SLAB];                   // 23.2 KB
  __shared__ float wsum[8][3];
  __shared__ double inv_s[12][12];
  __shared__ float fin_s[96 + BATCH];
  __shared__ int ticket_s;

  const int bc = blockIdx.x;
  const int t = threadIdx.x;
  const float* src = pf + (size_t)bc * SLAB;
  for (int i = t; i < SLAB; i += 512) S[i] = src[i];
  __syncthreads();

  float fmu = 0.f, fvar = 0.f, fg = 0.f;
  if (t < NP) {
    const int ph = t / NW, pw = t - ph * NW;
    const int h0 = 2 * ph;
#define AT(h, c, s) S[((h) * NCHUNK + (c)) * NSTAT + (s)]
    float S1 = 0.f, S2 = 0.f, Gx = 0.f, Gy = 0.f;
#pragma unroll
    for (int hh = 0; hh < 4; ++hh) {
      const int h = h0 + hh;
      S1 += AT(h, pw, 0) + AT(h, pw + 1, 0);
      S2 += AT(h, pw, 1) + AT(h, pw + 1, 1);
      Gx += AT(h, pw, 2) + AT(h, pw, 3) + AT(h, pw + 1, 2);
      Gy += AT(h, pw, 4) + AT(h, pw + 1, 4);
    }
#pragma unroll
    for (int hh = 0; hh < 3; ++hh) {
      const int h = h0 + hh;
      Gy += AT(h, pw, 5) + AT(h, pw + 1, 5);
    }
#undef AT
    fmu = S1 / NPIX;
    fvar = (S2 - S1 * S1 / NPIX) / (NPIX - 1.f);
    fg = sqrtf((Gx + Gy) / NGRAD);
  }
#pragma unroll
  for (int off = 32; off > 0; off >>= 1) {
    fmu += __shfl_xor(fmu, off);
    fvar += __shfl_xor(fvar, off);
    fg += __shfl_xor(fg, off);
  }
  const int wave = t >> 6;
  if ((t & 63) == 0) { wsum[wave][0] = fmu; wsum[wave][1] = fvar; wsum[wave][2] = fg; }
  __syncthreads();
  if (t == 0) {
    float m = 0.f, v = 0.f, g = 0.f;
#pragma unroll
    for (int w = 0; w < 8; ++w) { m += wsum[w][0]; v += wsum[w][1]; g += wsum[w][2]; }
    const int b = bc / CHAN, c = bc - b * CHAN;
    featsG[b * 12 + 0 + c] = m / (float)NP;
    featsG[b * 12 + 4 + c] = v / (float)NP;
    featsG[b * 12 + 8 + c] = g / (float)NP;
    __threadfence();                      // release featsG (32 fences: cheap)
    ticket_s = atomicAdd(cnt, 1);         // device-scope ticket
  }
  __syncthreads();
  if (ticket_s != NBC - 1) return;

  // ---- last block: finalize ----
  __threadfence();                        // acquire
  if (t < 96)
    fin_s[t] = __hip_atomic_load(&featsG[t], __ATOMIC_RELAXED,
                                 __HIP_MEMORY_SCOPE_AGENT);
  __syncthreads();

  if (t < 64) {   // wave 0: register-resident Gauss-Jordan, lane c owns col c
    double M[12];
#pragma unroll
    for (int r = 0; r < 12; ++r) {
      double v = 0.0;
      if (t < 12) v = (double)cov_full[r * 36 + t];
      else if (t < 24) v = (t - 12 == r) ? 1.0 : 0.0;
      M[r] = v;
    }
#pragma unroll
    for (int k = 0; k < 12; ++k) {
      const double piv = __shfl(M[k], k);
      const double ip = 1.0 / piv;
      M[k] *= ip;
#pragma unroll
      for (int r = 0; r < 12; ++r) {
        if (r == k) continue;
        const double f = __shfl(M[r], k);   // old M[r][k], read before update
        M[r] -= f * M[k];
      }
    }
    if (t >= 12 && t < 24) {
      const int j = t - 12;
#pragma unroll
      for (int r = 0; r < 12; ++r) inv_s[r][j] = M[r];
    }
  }
  __syncthreads();

  if (t < BATCH) {
    double acc = 0.0;
    double d[12];
#pragma unroll
    for (int i = 0; i < 12; ++i)
      d[i] = (double)fin_s[t * 12 + i] - (double)mu0_full[i];
#pragma unroll
    for (int i = 0; i < 12; ++i) {
      double row = 0.0;
#pragma unroll
      for (int j = 0; j < 12; ++j) row += inv_s[i][j] * d[j];
      acc += d[i] * row;
    }
    fin_s[96 + t] = (float)sqrt(acc);
  }
  __syncthreads();
  if (t == 0) {
    float m = 0.f;
#pragma unroll
    for (int b = 0; b < BATCH; ++b) m += fin_s[96 + b];
    out[0] = m / (float)BATCH;
  }
}

extern "C" void kernel_launch(void* const* d_in, const int* in_sizes, int n_in,
                              void* d_out, int out_size, void* d_ws, size_t ws_size,
                              hipStream_t stream) {
  const float* x   = (const float*)d_in[0];
  const float* mu0 = (const float*)d_in[1];
  const float* cov = (const float*)d_in[2];
  float* out = (float*)d_out;
  float* pf     = (float*)d_ws;                         // 32*5808 floats = 743 KB
  float* featsG = pf + (size_t)NBC * SLAB;              // 96 floats
  int* cnt      = (int*)(featsG + 96);                  // 1 ticket counter

  band_stats_kernel<<<NBC * NHB, 320, 0, stream>>>(x, pf, cnt);
  patch_finalize_kernel<<<NBC, 512, 0, stream>>>(pf, featsG, cnt, mu0, cov, out);
}